// Round 19
// baseline (159.301 us; speedup 1.0000x reference)
//
#include <hip/hip_runtime.h>

#define NKW   65536
#define NDOC  65536
#define NSEG  131072
#define NE    1048576
#define CHUNK 4096
#define NBLK  (NE / CHUNK)    // 256

typedef unsigned long long u64;
typedef unsigned short     u16;
typedef unsigned int       u32;
typedef unsigned char      u8;

typedef __attribute__((ext_vector_type(8))) short short8;   // 8 bf16
typedef __attribute__((ext_vector_type(4))) float f32x4;    // MFMA acc
typedef __attribute__((ext_vector_type(2))) float f32x2;

union U8 { short8 v; u64 u[2]; short s[8]; };

__device__ __forceinline__ u16 f2bf(float f) {              // RNE f32->bf16
    u32 u = __builtin_bit_cast(u32, f);
    u = (u + 0x7fffu + ((u >> 16) & 1u)) >> 16;
    return (u16)u;
}
__device__ __forceinline__ float bf2f(u16 h) {
    return __builtin_bit_cast(float, (u32)h << 16);
}
__device__ __forceinline__ u8 f2fp8(float f) {              // f32 -> fp8 e4m3 (OCP)
    u32 pk = __builtin_amdgcn_cvt_pk_fp8_f32(f, f, 0u, false);
    return (u8)pk;
}

// ---------------- workspace layout (bytes; ws >= 256MB) ----------------
// bufA: h0 fp8 (8MB). bufD: xdoc fp8 (8MB). bufB: g bf16 (16MB).
// bufC: pairs (8MB) -> agg outputs bf16 (16MB). bufE/bufF: gate hidden bf16.
#define BUFA_OFF 0ull
#define BUFD_OFF 8388608ull
#define BUFB_OFF 16777216ull
#define BUFC_OFF 33554432ull
#define WF_OFF   50331648ull            // 7 * 32KB fragment-packed weights
#define CSR_OFF  51380224ull            // 2*NE ints = 8 MB
#define CNT_OFF  59768832ull            // NSEG ints
#define AUX_OFF  60293120ull            // bhist[512] | bfill[512]
#define OFF_OFF  60821504ull            // NSEG ints
#define DIS_OFF  61345792ull            // NSEG floats
#define BUFE_OFF 67108864ull            // hidf bf16 16MB
#define BUFF_OFF 83886080ull            // hidt bf16 16MB

// packed-weight offsets (short8 units): matrix m at m*2048
#define WOFF_W0  0
#define WOFF_WG1 2048
#define WOFF_WG2 4096
#define WOFF_WF1 6144
#define WOFF_WF2 8192
#define WOFF_WT1 10240
#define WOFF_WT2 12288

struct PrepArgs { const float* w[7]; int K[7]; };

// ================= K0: zero bhist + bfill ======================================
__global__ void zero_k(int* __restrict__ p) {
    p[blockIdx.x * 256 + threadIdx.x] = 0;
}

// ================= K1: bucket histogram (blocks 0..255) + weight pre-pack =======
__global__ __launch_bounds__(256) void k1_hist_prep(
        const int* __restrict__ src, const int* __restrict__ dst,
        int* __restrict__ bhist, PrepArgs pa, short8* __restrict__ wfb) {
    __shared__ int h[512];
    const int tid = threadIdx.x;
    if (blockIdx.x < NBLK) {
        for (int i = tid; i < 512; i += 256) h[i] = 0;
        __syncthreads();
        int e0 = blockIdx.x * CHUNK;
        for (int i = tid; i < CHUNK; i += 256) {
            int s = src[e0 + i];
            int d = dst[e0 + i] - NKW;
            atomicAdd(&h[s >> 8], 1);
            atomicAdd(&h[256 + (d >> 8)], 1);
        }
        __syncthreads();
        for (int i = tid; i < 512; i += 256)
            if (h[i]) atomicAdd(&bhist[i], h[i]);
    } else {
        int u = (blockIdx.x - NBLK) * 4 + (tid >> 6);   // prepw unit 0..223
        if (u < 224) {
            int m = u >> 5, bk = u & 31;
            int kc = bk >> 3, ct = bk & 7;
            int l = tid & 63;
            int K = pa.K[m];
            const float* W = pa.w[m];
            U8 o;
            #pragma unroll
            for (int i = 0; i < 8; ++i) {
                int k   = kc * 32 + 4 * (l >> 4) + (i & 3) + 16 * (i >> 2);
                int col = ct * 16 + (l & 15);
                float v = (k < K) ? W[(size_t)k * 128 + col] : 0.f;
                o.s[i] = (short)f2bf(v);
            }
            wfb[(size_t)m * 2048 + bk * 64 + l] = o.v;
        }
    }
}

// ================= K2: part (0..255) | stage1f (256..1279) | stage1t (1280..2303)
// part: byte-identical to verified k2_part. stage1 branches: flat single-stage
// GEMMs (k7-shape), no LDS use, hidden-layer outputs to global bf16.
__global__ __launch_bounds__(256) void k2_part_s1(
        const int* __restrict__ src, const int* __restrict__ dst,
        const int* __restrict__ bhist, int* __restrict__ bfill,
        u32* __restrict__ pairs,
        const short8* __restrict__ wfb,
        const float* __restrict__ Xfb, const float* __restrict__ Xt,
        const float* __restrict__ bf1v, const float* __restrict__ bt1v,
        u16* __restrict__ hidf, u16* __restrict__ hidt) {
    __shared__ int h[512], sc[512], base[512], gb[512];
    __shared__ u32 staged[2 * CHUNK];
    const int tid = threadIdx.x;

    if (blockIdx.x < NBLK) {
        // ---------------- part branch (unchanged) ----------------
        for (int i = tid; i < 512; i += 256) gb[i] = bhist[i];
        __syncthreads();
        for (int d = 1; d < 512; d <<= 1) {
            int i1 = tid + 256;
            int t0 = (tid >= d) ? gb[tid - d] : 0;
            int t1 = gb[i1 - d];
            __syncthreads();
            gb[tid] += t0; gb[i1] += t1;
            __syncthreads();
        }
        for (int i = tid; i < 512; i += 256) gb[i] -= bhist[i];   // exclusive base
        for (int i = tid; i < 512; i += 256) h[i] = 0;
        __syncthreads();

        const int e0 = blockIdx.x * CHUNK;
        int se[16], de[16];
        #pragma unroll
        for (int j = 0; j < 16; ++j) {
            int e = e0 + tid + j * 256;
            se[j] = src[e];
            de[j] = dst[e] - NKW;
            atomicAdd(&h[se[j] >> 8], 1);
            atomicAdd(&h[256 + (de[j] >> 8)], 1);
        }
        __syncthreads();

        sc[tid] = h[tid];
        __syncthreads();
        for (int d = 1; d < 256; d <<= 1) {
            int t = (tid >= d) ? sc[tid - d] : 0;
            __syncthreads();
            sc[tid] += t;
            __syncthreads();
        }
        sc[256 + tid] = h[256 + tid];
        __syncthreads();
        for (int d = 1; d < 256; d <<= 1) {
            int t = (tid >= d) ? sc[256 + tid - d] : 0;
            __syncthreads();
            sc[256 + tid] += t;
            __syncthreads();
        }

        for (int i = tid; i < 512; i += 256) {
            base[i] = gb[i] + atomicAdd(&bfill[i], h[i]);
            sc[i] -= h[i];
            h[i] = 0;
        }
        __syncthreads();

        #pragma unroll
        for (int j = 0; j < 16; ++j) {
            int bk = se[j] >> 8;
            int r  = atomicAdd(&h[bk], 1);
            staged[sc[bk] + r] = ((u32)(se[j] & 255) << 16) | (u32)de[j];
            int bd = 256 + (de[j] >> 8);
            int r2 = atomicAdd(&h[bd], 1);
            staged[CHUNK + sc[bd] + r2] = ((u32)(de[j] & 255) << 16) | (u32)se[j];
        }
        __syncthreads();

        for (int i = tid; i < 512; i += 256) {
            int n = h[i];
            int so = (i < 256 ? 0 : CHUNK) + sc[i];
            u32* dp = pairs + base[i];
            for (int j = 0; j < n; ++j) dp[j] = staged[so + j];
        }
        return;
    }

    const int w = tid >> 6, l = tid & 63, lr = l & 15, q = l >> 4;
    f32x4 acc[8];
    #pragma unroll
    for (int ct = 0; ct < 8; ++ct) acc[ct] = (f32x4){0.f, 0.f, 0.f, 0.f};

    if (blockIdx.x < NBLK + 1024) {
        // ---------------- stage1f: hidf = relu(Xfb @ Wf1 + bf1), K=16 ----------
        const int blk = blockIdx.x - NBLK;
        const int row = blk * 64 + w * 16 + lr;
        U8 a;
        f32x4 x = *(const f32x4*)(Xfb + (size_t)row * 16 + 4 * q);  // kb=4q<16
        #pragma unroll
        for (int i = 0; i < 4; ++i) { a.s[i] = (short)f2bf(x[i]); a.s[4 + i] = 0; }
        #pragma unroll
        for (int ct = 0; ct < 8; ++ct)
            acc[ct] = __builtin_amdgcn_mfma_f32_16x16x32_bf16(
                          a.v, wfb[WOFF_WF1 + ct * 64 + l], acc[ct], 0, 0, 0);
        const int orow0 = blk * 64 + w * 16 + 4 * q;
        #pragma unroll
        for (int ct = 0; ct < 8; ++ct) {
            const int col = ct * 16 + lr;
            const float bb = bf1v[col];
            #pragma unroll
            for (int r = 0; r < 4; ++r)
                hidf[(size_t)(orow0 + r) * 128 + col] = f2bf(fmaxf(acc[ct][r] + bb, 0.f));
        }
    } else {
        // ---------------- stage1t: hidt = relu(Xt @ Wt1 + bt1), K=8 ------------
        const int blk = blockIdx.x - NBLK - 1024;
        const int row = blk * 64 + w * 16 + lr;
        U8 a;
        #pragma unroll
        for (int i = 0; i < 8; ++i) a.s[i] = 0;
        if (q < 2) {
            f32x4 x = *(const f32x4*)(Xt + (size_t)row * 8 + 4 * q);
            #pragma unroll
            for (int i = 0; i < 4; ++i) a.s[i] = (short)f2bf(x[i]);
        }
        #pragma unroll
        for (int ct = 0; ct < 8; ++ct)
            acc[ct] = __builtin_amdgcn_mfma_f32_16x16x32_bf16(
                          a.v, wfb[WOFF_WT1 + ct * 64 + l], acc[ct], 0, 0, 0);
        const int orow0 = blk * 64 + w * 16 + 4 * q;
        #pragma unroll
        for (int ct = 0; ct < 8; ++ct) {
            const int col = ct * 16 + lr;
            const float bb = bt1v[col];
            #pragma unroll
            for (int r = 0; r < 4; ++r)
                hidt[(size_t)(orow0 + r) * 128 + col] = f2bf(fmaxf(acc[ct][r] + bb, 0.f));
        }
    }
}

// ================= K3: build (0..511) | gemm0 (512..1535) | stage2 (1536..2559) =
// stage2: g = (hidf@Wf2+bf2) * (hidt@Wt2+bt2), flat, global-staged.
__global__ __launch_bounds__(256) void k3_build_gemm0_s2(
        const u32* __restrict__ pairs, const int* __restrict__ bhist,
        int* __restrict__ off, int* __restrict__ cnt,
        float* __restrict__ dis, int* __restrict__ csr,
        const float* __restrict__ Xn, const short8* __restrict__ wfb,
        const float* __restrict__ b0, u8* __restrict__ h0f8,
        const u16* __restrict__ hidf, const u16* __restrict__ hidt,
        const float* __restrict__ bf2v, const float* __restrict__ bt2v,
        u16* __restrict__ g) {
    __shared__ int lcnt[256], loff[256], bs[256], gsc[512];
    const int tid = threadIdx.x;

    if (blockIdx.x < 512) {
        // ---------------- build branch (unchanged) ----------------
        const int b = blockIdx.x;
        for (int i = tid; i < 512; i += 256) gsc[i] = bhist[i];
        __syncthreads();
        for (int d = 1; d < 512; d <<= 1) {
            int i1 = tid + 256;
            int t0 = (tid >= d) ? gsc[tid - d] : 0;
            int t1 = gsc[i1 - d];
            __syncthreads();
            gsc[tid] += t0; gsc[i1] += t1;
            __syncthreads();
        }
        const int size  = bhist[b];
        const int start = gsc[b] - size;      // exclusive
        lcnt[tid] = 0;
        __syncthreads();
        for (int i = tid; i < size; i += 256)
            atomicAdd(&lcnt[(pairs[start + i] >> 16) & 255], 1);
        __syncthreads();
        int s = lcnt[tid];
        bs[tid] = s;
        __syncthreads();
        for (int d = 1; d < 256; d <<= 1) {
            int t = (tid >= d) ? bs[tid - d] : 0;
            __syncthreads();
            bs[tid] += t;
            __syncthreads();
        }
        const int P = bs[tid] - s;
        const int seg = (b < 256) ? (b * 256 + tid) : (NKW + (b - 256) * 256 + tid);
        off[seg] = start + P;
        cnt[seg] = s;
        dis[seg] = rsqrtf((float)(s + 1));
        loff[tid] = P;
        lcnt[tid] = 0;
        __syncthreads();
        for (int i = tid; i < size; i += 256) {
            u32 p = pairs[start + i];
            int key = (p >> 16) & 255;
            int r = atomicAdd(&lcnt[key], 1);
            csr[start + loff[key] + r] = (int)(p & 0xFFFF);
        }
        return;
    }

    const int w = tid >> 6, l = tid & 63, lr = l & 15, q = l >> 4;

    if (blockIdx.x < 1536) {
        // ---------------- layer-0 GEMM branch (unchanged) ----------------
        const int blk = blockIdx.x - 512;
        const int row = blk * 64 + w * 16 + lr;
        f32x4 acc[8];
        #pragma unroll
        for (int ct = 0; ct < 8; ++ct) acc[ct] = (f32x4){0.f, 0.f, 0.f, 0.f};
        #pragma unroll
        for (int kc = 0; kc < 4; ++kc) {
            U8 a;
            const int kb = kc * 32 + 4 * q;
            const float* A = Xn + (size_t)row * 128;
            f32x4 lo = *(const f32x4*)(A + kb);
            f32x4 hi = *(const f32x4*)(A + kb + 16);
            #pragma unroll
            for (int i = 0; i < 4; ++i) {
                a.s[i]     = (short)f2bf(lo[i]);
                a.s[4 + i] = (short)f2bf(hi[i]);
            }
            #pragma unroll
            for (int ct = 0; ct < 8; ++ct)
                acc[ct] = __builtin_amdgcn_mfma_f32_16x16x32_bf16(
                              a.v, wfb[WOFF_W0 + (kc * 8 + ct) * 64 + l], acc[ct], 0, 0, 0);
        }
        const int orow0 = blk * 64 + w * 16 + 4 * q;
        #pragma unroll
        for (int ct = 0; ct < 8; ++ct) {
            const int col = ct * 16 + lr;
            const float bb = b0[col];
            #pragma unroll
            for (int r = 0; r < 4; ++r) {
                float v = fmaxf(acc[ct][r] + bb, 0.f);
                h0f8[(size_t)(orow0 + r) * 128 + col] = f2fp8(v);
            }
        }
        return;
    }

    // ---------------- stage2: g = (hidf@Wf2+bf2) * (hidt@Wt2+bt2) --------------
    const int blk = blockIdx.x - 1536;
    const int row = blk * 64 + w * 16 + lr;
    f32x4 accf[8], acct[8];
    #pragma unroll
    for (int ct = 0; ct < 8; ++ct) {
        accf[ct] = (f32x4){0.f, 0.f, 0.f, 0.f};
        acct[ct] = (f32x4){0.f, 0.f, 0.f, 0.f};
    }
    #pragma unroll
    for (int kc = 0; kc < 4; ++kc) {
        const int kb = kc * 32 + 4 * q;
        U8 a;
        const u16* Af = hidf + (size_t)row * 128;
        a.u[0] = *(const u64*)(Af + kb);
        a.u[1] = *(const u64*)(Af + kb + 16);
        #pragma unroll
        for (int ct = 0; ct < 8; ++ct)
            accf[ct] = __builtin_amdgcn_mfma_f32_16x16x32_bf16(
                           a.v, wfb[WOFF_WF2 + (kc * 8 + ct) * 64 + l], accf[ct], 0, 0, 0);
        const u16* At = hidt + (size_t)row * 128;
        a.u[0] = *(const u64*)(At + kb);
        a.u[1] = *(const u64*)(At + kb + 16);
        #pragma unroll
        for (int ct = 0; ct < 8; ++ct)
            acct[ct] = __builtin_amdgcn_mfma_f32_16x16x32_bf16(
                           a.v, wfb[WOFF_WT2 + (kc * 8 + ct) * 64 + l], acct[ct], 0, 0, 0);
    }
    const int orow0 = blk * 64 + w * 16 + 4 * q;
    #pragma unroll
    for (int ct = 0; ct < 8; ++ct) {
        const int col = ct * 16 + lr;
        const float b2f = bf2v[col];
        const float b2t = bt2v[col];
        #pragma unroll
        for (int r = 0; r < 4; ++r) {
            float gv = (accf[ct][r] + b2f) * (acct[ct][r] + b2t);
            g[(size_t)(orow0 + r) * 128 + col] = f2bf(gv);
        }
    }
}

// ================= agg: fp8 aggregation (16 lanes/row = one 128B line/edge) =====
template<bool KW_SIDE>
__global__ __launch_bounds__(256) void aggf8_k(
        const int* __restrict__ off, const int* __restrict__ cnt,
        const int* __restrict__ csr, const u8* __restrict__ gsrc,
        const u8* __restrict__ h0f8, const float* __restrict__ dis,
        u16* __restrict__ outb) {
    const int r    = blockIdx.x * 16 + (threadIdx.x >> 4);
    const int lane = threadIdx.x & 15;
    const int seg  = KW_SIDE ? r : (NKW + r);
    const int st = off[seg];
    const int n  = cnt[seg];
    float a[8];
    #pragma unroll
    for (int j = 0; j < 8; ++j) a[j] = 0.f;

    #define DECACC(vv) { \
        u32 lo_ = (u32)(vv), hi_ = (u32)((vv) >> 32); \
        f32x2 p0 = __builtin_amdgcn_cvt_pk_f32_fp8(lo_, false); \
        f32x2 p1 = __builtin_amdgcn_cvt_pk_f32_fp8(lo_, true);  \
        f32x2 p2 = __builtin_amdgcn_cvt_pk_f32_fp8(hi_, false); \
        f32x2 p3 = __builtin_amdgcn_cvt_pk_f32_fp8(hi_, true);  \
        a[0] += p0[0]; a[1] += p0[1]; a[2] += p1[0]; a[3] += p1[1]; \
        a[4] += p2[0]; a[5] += p2[1]; a[6] += p3[0]; a[7] += p3[1]; }

    int i = 0;
    for (; i + 8 <= n; i += 8) {                  // 8 gathers in flight
        int nb[8];
        #pragma unroll
        for (int k = 0; k < 8; ++k) nb[k] = csr[st + i + k];
        u64 v[8];
        #pragma unroll
        for (int k = 0; k < 8; ++k)
            v[k] = *(const u64*)(gsrc + (size_t)nb[k] * 128 + lane * 8);
        #pragma unroll
        for (int k = 0; k < 8; ++k) DECACC(v[k])
    }
    for (; i < n; ++i) {
        int nb = csr[st + i];
        u64 v = *(const u64*)(gsrc + (size_t)nb * 128 + lane * 8);
        DECACC(v)
    }
    #undef DECACC

    const float dk = dis[seg];
    if (KW_SIDE) {
        u64 hv = *(const u64*)(h0f8 + (size_t)r * 128 + lane * 8);
        u32 lo_ = (u32)hv, hi_ = (u32)(hv >> 32);
        f32x2 p0 = __builtin_amdgcn_cvt_pk_f32_fp8(lo_, false);
        f32x2 p1 = __builtin_amdgcn_cvt_pk_f32_fp8(lo_, true);
        f32x2 p2 = __builtin_amdgcn_cvt_pk_f32_fp8(hi_, false);
        f32x2 p3 = __builtin_amdgcn_cvt_pk_f32_fp8(hi_, true);
        float hh[8] = {p0[0], p0[1], p1[0], p1[1], p2[0], p2[1], p3[0], p3[1]};
        #pragma unroll
        for (int j = 0; j < 8; ++j) a[j] = dk * (a[j] + dk * hh[j]);
    } else {
        #pragma unroll
        for (int j = 0; j < 8; ++j) a[j] *= dk;
    }
    U8 o;
    #pragma unroll
    for (int j = 0; j < 8; ++j) o.s[j] = (short)f2bf(a[j]);
    *(short8*)(outb + (size_t)r * 128 + lane * 8) = o.v;
}

// ================= K7: layer-1 GEMM + g multiply; writes xdoc fp8 ===============
__global__ __launch_bounds__(256) void k7_gemm1g(
        const u16* __restrict__ aggin, const short8* __restrict__ wfb,
        const float* __restrict__ bg1, const u16* __restrict__ gmul,
        u8* __restrict__ xdocf8, float* __restrict__ outdoc) {
    const int tid = threadIdx.x;
    const int w = tid >> 6, l = tid & 63, lr = l & 15, q = l >> 4;
    const int row = blockIdx.x * 64 + w * 16 + lr;
    f32x4 acc[8];
    #pragma unroll
    for (int ct = 0; ct < 8; ++ct) acc[ct] = (f32x4){0.f, 0.f, 0.f, 0.f};
    #pragma unroll
    for (int kc = 0; kc < 4; ++kc) {
        U8 a;
        const int kb = kc * 32 + 4 * q;
        const u16* A = aggin + (size_t)row * 128;
        a.u[0] = *(const u64*)(A + kb);
        a.u[1] = *(const u64*)(A + kb + 16);
        #pragma unroll
        for (int ct = 0; ct < 8; ++ct)
            acc[ct] = __builtin_amdgcn_mfma_f32_16x16x32_bf16(
                          a.v, wfb[WOFF_WG1 + (kc * 8 + ct) * 64 + l], acc[ct], 0, 0, 0);
    }
    const int orow0 = blockIdx.x * 64 + w * 16 + 4 * q;
    #pragma unroll
    for (int ct = 0; ct < 8; ++ct) {
        const int col = ct * 16 + lr;
        const float bb = bg1[col];
        #pragma unroll
        for (int r = 0; r < 4; ++r) {
            float v = fmaxf(acc[ct][r] + bb, 0.f);
            const size_t idx = (size_t)(orow0 + r) * 128 + col;
            xdocf8[idx] = f2fp8(v);
            float o = v * bf2f(gmul[idx]);
            __builtin_nontemporal_store(o, outdoc + idx);
        }
    }
}

// ================= K8: layer-2 GEMM (bf16 in, fp32 out) =========================
__global__ __launch_bounds__(256) void k8_gemm2(
        const u16* __restrict__ Av, const short8* __restrict__ wfb,
        const float* __restrict__ bg2, float* __restrict__ outf32) {
    const int tid = threadIdx.x;
    const int w = tid >> 6, l = tid & 63, lr = l & 15, q = l >> 4;
    const int row = blockIdx.x * 64 + w * 16 + lr;
    f32x4 acc[8];
    #pragma unroll
    for (int ct = 0; ct < 8; ++ct) acc[ct] = (f32x4){0.f, 0.f, 0.f, 0.f};
    #pragma unroll
    for (int kc = 0; kc < 4; ++kc) {
        U8 a;
        const int kb = kc * 32 + 4 * q;
        const u16* A = Av + (size_t)row * 128;
        a.u[0] = *(const u64*)(A + kb);
        a.u[1] = *(const u64*)(A + kb + 16);
        #pragma unroll
        for (int ct = 0; ct < 8; ++ct)
            acc[ct] = __builtin_amdgcn_mfma_f32_16x16x32_bf16(
                          a.v, wfb[WOFF_WG2 + (kc * 8 + ct) * 64 + l], acc[ct], 0, 0, 0);
    }
    const int orow0 = blockIdx.x * 64 + w * 16 + 4 * q;
    #pragma unroll
    for (int ct = 0; ct < 8; ++ct) {
        const int col = ct * 16 + lr;
        const float bb = bg2[col];
        #pragma unroll
        for (int r = 0; r < 4; ++r) {
            float v = fmaxf(acc[ct][r] + bb, 0.f);
            __builtin_nontemporal_store(v, outf32 + (size_t)(orow0 + r) * 128 + col);
        }
    }
}

extern "C" void kernel_launch(void* const* d_in, const int* in_sizes, int n_in,
                              void* d_out, int out_size, void* d_ws, size_t ws_size,
                              hipStream_t stream) {
    const float* Xn  = (const float*)d_in[0];
    const float* Xfb = (const float*)d_in[1];
    const float* Xt  = (const float*)d_in[2];
    const int*   e01 = (const int*)d_in[3];
    const float* W0  = (const float*)d_in[6];
    const float* b0  = (const float*)d_in[7];
    const float* Wg1 = (const float*)d_in[8];
    const float* bg1 = (const float*)d_in[9];
    const float* Wg2 = (const float*)d_in[10];
    const float* bg2 = (const float*)d_in[11];
    const float* Wf1 = (const float*)d_in[12];
    const float* bf1 = (const float*)d_in[13];
    const float* Wf2 = (const float*)d_in[14];
    const float* bf2 = (const float*)d_in[15];
    const float* Wt1 = (const float*)d_in[16];
    const float* bt1 = (const float*)d_in[17];
    const float* Wt2 = (const float*)d_in[18];
    const float* bt2 = (const float*)d_in[19];

    float* out = (float*)d_out;
    char*  ws  = (char*)d_ws;
    u8*    bufA  = (u8*)(ws + BUFA_OFF);      // h0 fp8
    u8*    bufD  = (u8*)(ws + BUFD_OFF);      // xdoc fp8
    u16*   bufB  = (u16*)(ws + BUFB_OFF);     // g bf16
    u16*   bufC  = (u16*)(ws + BUFC_OFF);     // pairs -> agg outputs bf16
    u32*   pairs = (u32*)(ws + BUFC_OFF);
    short8* wfb  = (short8*)(ws + WF_OFF);
    int*   csr   = (int*)(ws + CSR_OFF);
    int*   cnt   = (int*)(ws + CNT_OFF);
    int*   bhist = (int*)(ws + AUX_OFF);
    int*   bfill = bhist + 512;
    int*   off   = (int*)(ws + OFF_OFF);
    float* dis   = (float*)(ws + DIS_OFF);
    u16*   bufE  = (u16*)(ws + BUFE_OFF);     // hidf bf16
    u16*   bufF  = (u16*)(ws + BUFF_OFF);     // hidt bf16

    const int* src = e01;
    const int* dst = e01 + NE;

    PrepArgs pa;
    pa.w[0] = W0;  pa.K[0] = 128;
    pa.w[1] = Wg1; pa.K[1] = 128;
    pa.w[2] = Wg2; pa.K[2] = 128;
    pa.w[3] = Wf1; pa.K[3] = 16;
    pa.w[4] = Wf2; pa.K[4] = 128;
    pa.w[5] = Wt1; pa.K[5] = 8;
    pa.w[6] = Wt2; pa.K[6] = 128;

    zero_k<<<4, 256, 0, stream>>>(bhist);                         // bhist + bfill
    k1_hist_prep<<<NBLK + 56, 256, 0, stream>>>(src, dst, bhist, pa, wfb);
    // part + gate stage-1 (flat): independent work fills idle CUs
    k2_part_s1<<<NBLK + 2048, 256, 0, stream>>>(
        src, dst, bhist, bfill, pairs,
        wfb, Xfb, Xt, bf1, bt1, bufE, bufF);
    // build + gemm0 + gate stage-2 (flat)
    k3_build_gemm0_s2<<<512 + 2048, 256, 0, stream>>>(
        pairs, bhist, off, cnt, dis, csr, Xn, wfb, b0, bufA,
        bufE, bufF, bf2, bt2, bufB);

    // layer 1: agg(h0 fp8) -> bufC bf16; GEMM + g multiply -> out_doc + xdoc fp8
    aggf8_k<false><<<NDOC / 16, 256, 0, stream>>>(off, cnt, csr, bufA, nullptr, dis, bufC);
    k7_gemm1g<<<1024, 256, 0, stream>>>(bufC, wfb, bg1, bufB, bufD,
                                        out + (size_t)NKW * 128);

    // layer 2: agg(xdoc fp8) + dk^2*h0(fp8) -> bufC bf16; GEMM -> out_kw fp32
    aggf8_k<true><<<NKW / 16, 256, 0, stream>>>(off, cnt, csr, bufD, bufA, dis, bufC);
    k8_gemm2<<<1024, 256, 0, stream>>>(bufC, wfb, bg2, out);
}

// Round 20
// 155.503 us; speedup vs baseline: 1.0244x; 1.0244x over previous
//
#include <hip/hip_runtime.h>

#define NKW   65536
#define NDOC  65536
#define NSEG  131072
#define NE    1048576
#define CHUNK 4096
#define NBLK  (NE / CHUNK)    // 256

typedef unsigned long long u64;
typedef unsigned short     u16;
typedef unsigned int       u32;
typedef unsigned char      u8;

typedef __attribute__((ext_vector_type(8))) short short8;   // 8 bf16
typedef __attribute__((ext_vector_type(4))) float f32x4;    // MFMA acc
typedef __attribute__((ext_vector_type(2))) float f32x2;

union U8 { short8 v; u64 u[2]; short s[8]; };

__device__ __forceinline__ u16 f2bf(float f) {              // RNE f32->bf16
    u32 u = __builtin_bit_cast(u32, f);
    u = (u + 0x7fffu + ((u >> 16) & 1u)) >> 16;
    return (u16)u;
}
__device__ __forceinline__ float bf2f(u16 h) {
    return __builtin_bit_cast(float, (u32)h << 16);
}
__device__ __forceinline__ u8 f2fp8(float f) {              // f32 -> fp8 e4m3 (OCP)
    u32 pk = __builtin_amdgcn_cvt_pk_fp8_f32(f, f, 0u, false);
    return (u8)pk;
}

// ---------------- workspace layout (bytes) ----------------
// bufA: h0 fp8 (8MB). bufD: xdoc fp8 (8MB). bufB: g bf16 (16MB).
// bufC: pairs (8MB) -> agg1-out bf16 -> agg2-out bf16 (16MB).
#define BUFA_OFF 0ull
#define BUFD_OFF 8388608ull
#define BUFB_OFF 16777216ull
#define BUFC_OFF 33554432ull
#define WF_OFF   50331648ull            // 7 * 32KB fragment-packed weights
#define CSR_OFF  51380224ull            // 2*NE ints = 8 MB
#define CNT_OFF  59768832ull            // NSEG ints
#define AUX_OFF  60293120ull            // bhist[512] | bfill[512]
#define OFF_OFF  60821504ull            // NSEG ints
#define DIS_OFF  61345792ull            // NSEG floats

// packed-weight offsets (short8 units): matrix m at m*2048
#define WOFF_W0  0
#define WOFF_WG1 2048
#define WOFF_WG2 4096
#define WOFF_WF1 6144
#define WOFF_WF2 8192
#define WOFF_WT1 10240
#define WOFF_WT2 12288

struct PrepArgs { const float* w[7]; int K[7]; };

// ================= K0: zero bhist + bfill ======================================
__global__ void zero_k(int* __restrict__ p) {
    p[blockIdx.x * 256 + threadIdx.x] = 0;
}

// ================= K1: bucket histogram (blocks 0..255) + weight pre-pack =======
__global__ __launch_bounds__(256) void k1_hist_prep(
        const int* __restrict__ src, const int* __restrict__ dst,
        int* __restrict__ bhist, PrepArgs pa, short8* __restrict__ wfb) {
    __shared__ int h[512];
    const int tid = threadIdx.x;
    if (blockIdx.x < NBLK) {
        for (int i = tid; i < 512; i += 256) h[i] = 0;
        __syncthreads();
        int e0 = blockIdx.x * CHUNK;
        for (int i = tid; i < CHUNK; i += 256) {
            int s = src[e0 + i];
            int d = dst[e0 + i] - NKW;
            atomicAdd(&h[s >> 8], 1);
            atomicAdd(&h[256 + (d >> 8)], 1);
        }
        __syncthreads();
        for (int i = tid; i < 512; i += 256)
            if (h[i]) atomicAdd(&bhist[i], h[i]);
    } else {
        int u = (blockIdx.x - NBLK) * 4 + (tid >> 6);   // prepw unit 0..223
        if (u < 224) {
            int m = u >> 5, bk = u & 31;
            int kc = bk >> 3, ct = bk & 7;
            int l = tid & 63;
            int K = pa.K[m];
            const float* W = pa.w[m];
            U8 o;
            #pragma unroll
            for (int i = 0; i < 8; ++i) {
                int k   = kc * 32 + 4 * (l >> 4) + (i & 3) + 16 * (i >> 2);
                int col = ct * 16 + (l & 15);
                float v = (k < K) ? W[(size_t)k * 128 + col] : 0.f;
                o.s[i] = (short)f2bf(v);
            }
            wfb[(size_t)m * 2048 + bk * 64 + l] = o.v;
        }
    }
}

// ================= K2: edge partition (blocks 0..255) + gates (256..1279) =======
// part branch: byte-identical to verified k2_part. gates branch: byte-identical
// to R17's fenced wave-independent gates; its 17.4KB LDS tile is OVERLAID on
// the part branch's 32KB `staged` (different blocks, never both live).
__global__ __launch_bounds__(256) void k2_part_gates(
        const int* __restrict__ src, const int* __restrict__ dst,
        const int* __restrict__ bhist, int* __restrict__ bfill,
        u32* __restrict__ pairs,
        const short8* __restrict__ wfb,
        const float* __restrict__ Xfb, const float* __restrict__ Xt,
        const float* __restrict__ bf1v, const float* __restrict__ bf2v,
        const float* __restrict__ bt1v, const float* __restrict__ bt2v,
        u16* __restrict__ g) {
    __shared__ int h[512], sc[512], base[512], gb[512];
    __shared__ u32 staged[2 * CHUNK];
    const int tid = threadIdx.x;

    if (blockIdx.x < NBLK) {
        // ---------------- part branch ----------------
        for (int i = tid; i < 512; i += 256) gb[i] = bhist[i];
        __syncthreads();
        for (int d = 1; d < 512; d <<= 1) {
            int i1 = tid + 256;
            int t0 = (tid >= d) ? gb[tid - d] : 0;
            int t1 = gb[i1 - d];
            __syncthreads();
            gb[tid] += t0; gb[i1] += t1;
            __syncthreads();
        }
        for (int i = tid; i < 512; i += 256) gb[i] -= bhist[i];   // exclusive base
        for (int i = tid; i < 512; i += 256) h[i] = 0;
        __syncthreads();

        const int e0 = blockIdx.x * CHUNK;
        int se[16], de[16];
        #pragma unroll
        for (int j = 0; j < 16; ++j) {
            int e = e0 + tid + j * 256;
            se[j] = src[e];
            de[j] = dst[e] - NKW;
            atomicAdd(&h[se[j] >> 8], 1);
            atomicAdd(&h[256 + (de[j] >> 8)], 1);
        }
        __syncthreads();

        sc[tid] = h[tid];
        __syncthreads();
        for (int d = 1; d < 256; d <<= 1) {
            int t = (tid >= d) ? sc[tid - d] : 0;
            __syncthreads();
            sc[tid] += t;
            __syncthreads();
        }
        sc[256 + tid] = h[256 + tid];
        __syncthreads();
        for (int d = 1; d < 256; d <<= 1) {
            int t = (tid >= d) ? sc[256 + tid - d] : 0;
            __syncthreads();
            sc[256 + tid] += t;
            __syncthreads();
        }

        for (int i = tid; i < 512; i += 256) {
            base[i] = gb[i] + atomicAdd(&bfill[i], h[i]);
            sc[i] -= h[i];
            h[i] = 0;
        }
        __syncthreads();

        #pragma unroll
        for (int j = 0; j < 16; ++j) {
            int bk = se[j] >> 8;
            int r  = atomicAdd(&h[bk], 1);
            staged[sc[bk] + r] = ((u32)(se[j] & 255) << 16) | (u32)de[j];
            int bd = 256 + (de[j] >> 8);
            int r2 = atomicAdd(&h[bd], 1);
            staged[CHUNK + sc[bd] + r2] = ((u32)(de[j] & 255) << 16) | (u32)se[j];
        }
        __syncthreads();

        for (int i = tid; i < 512; i += 256) {
            int n = h[i];
            int so = (i < 256 ? 0 : CHUNK) + sc[i];
            u32* dp = pairs + base[i];
            for (int j = 0; j < n; ++j) dp[j] = staged[so + j];
        }
        return;
    }

    // ---------------- gates branch (wave-independent, fenced) ----------------
    u16 (*H)[136] = (u16(*)[136])staged;          // 17408B overlay on 32KB staged
    const int w = tid >> 6, l = tid & 63, lr = l & 15, q = l >> 4;
    const int blk  = blockIdx.x - NBLK;
    const int row0 = blk * 64 + w * 16;
    const int lrow = w * 16 + lr;
    const int orow = w * 16 + 4 * q;

    f32x4 acc[8];
    // stage 1f: relu(Xfb @ Wf1 + bf1) -> H
    {
        U8 a;
        f32x4 x = *(const f32x4*)(Xfb + (size_t)(row0 + lr) * 16 + 4 * q);  // K=16
        #pragma unroll
        for (int i = 0; i < 4; ++i) { a.s[i] = (short)f2bf(x[i]); a.s[4 + i] = 0; }
        #pragma unroll
        for (int ct = 0; ct < 8; ++ct)
            acc[ct] = __builtin_amdgcn_mfma_f32_16x16x32_bf16(
                          a.v, wfb[WOFF_WF1 + ct * 64 + l], (f32x4){0.f,0.f,0.f,0.f}, 0, 0, 0);
    }
    #pragma unroll
    for (int ct = 0; ct < 8; ++ct) {
        const int col = ct * 16 + lr;
        const float bb = bf1v[col];
        #pragma unroll
        for (int r = 0; r < 4; ++r)
            H[orow + r][col] = f2bf(fmaxf(acc[ct][r] + bb, 0.f));
    }
    __threadfence_block();

    // stage 2f: H @ Wf2 -> accf
    f32x4 accf[8];
    #pragma unroll
    for (int ct = 0; ct < 8; ++ct) accf[ct] = (f32x4){0.f, 0.f, 0.f, 0.f};
    #pragma unroll
    for (int kc = 0; kc < 4; ++kc) {
        U8 a;
        const int kb = kc * 32 + 4 * q;
        a.u[0] = *(const u64*)&H[lrow][kb];
        a.u[1] = *(const u64*)&H[lrow][kb + 16];
        #pragma unroll
        for (int ct = 0; ct < 8; ++ct)
            accf[ct] = __builtin_amdgcn_mfma_f32_16x16x32_bf16(
                           a.v, wfb[WOFF_WF2 + (kc * 8 + ct) * 64 + l], accf[ct], 0, 0, 0);
    }
    __threadfence_block();

    // stage 1t: relu(Xt @ Wt1 + bt1) -> H
    {
        U8 a;
        #pragma unroll
        for (int i = 0; i < 8; ++i) a.s[i] = 0;
        if (q < 2) {                               // K=8
            f32x4 x = *(const f32x4*)(Xt + (size_t)(row0 + lr) * 8 + 4 * q);
            #pragma unroll
            for (int i = 0; i < 4; ++i) a.s[i] = (short)f2bf(x[i]);
        }
        #pragma unroll
        for (int ct = 0; ct < 8; ++ct)
            acc[ct] = __builtin_amdgcn_mfma_f32_16x16x32_bf16(
                          a.v, wfb[WOFF_WT1 + ct * 64 + l], (f32x4){0.f,0.f,0.f,0.f}, 0, 0, 0);
    }
    #pragma unroll
    for (int ct = 0; ct < 8; ++ct) {
        const int col = ct * 16 + lr;
        const float bb = bt1v[col];
        #pragma unroll
        for (int r = 0; r < 4; ++r)
            H[orow + r][col] = f2bf(fmaxf(acc[ct][r] + bb, 0.f));
    }
    __threadfence_block();

    // stage 2t + epilogue: g = (accf+bf2) * (acct+bt2)
    f32x4 acct[8];
    #pragma unroll
    for (int ct = 0; ct < 8; ++ct) acct[ct] = (f32x4){0.f, 0.f, 0.f, 0.f};
    #pragma unroll
    for (int kc = 0; kc < 4; ++kc) {
        U8 a;
        const int kb = kc * 32 + 4 * q;
        a.u[0] = *(const u64*)&H[lrow][kb];
        a.u[1] = *(const u64*)&H[lrow][kb + 16];
        #pragma unroll
        for (int ct = 0; ct < 8; ++ct)
            acct[ct] = __builtin_amdgcn_mfma_f32_16x16x32_bf16(
                           a.v, wfb[WOFF_WT2 + (kc * 8 + ct) * 64 + l], acct[ct], 0, 0, 0);
    }
    #pragma unroll
    for (int ct = 0; ct < 8; ++ct) {
        const int col = ct * 16 + lr;
        const float b2f = bf2v[col];
        const float b2t = bt2v[col];
        #pragma unroll
        for (int r = 0; r < 4; ++r) {
            float gv = (accf[ct][r] + b2f) * (acct[ct][r] + b2t);
            g[(size_t)(blk * 64 + orow + r) * 128 + col] = f2bf(gv);
        }
    }
}

// ================= K3: CSR build (blocks 0..511) + layer-0 GEMM (512..1535) =====
__global__ __launch_bounds__(256) void k3_build_gemm0(
        const u32* __restrict__ pairs, const int* __restrict__ bhist,
        int* __restrict__ off, int* __restrict__ cnt,
        float* __restrict__ dis, int* __restrict__ csr,
        const float* __restrict__ Xn, const short8* __restrict__ wfb,
        const float* __restrict__ b0, u8* __restrict__ h0f8) {
    __shared__ int lcnt[256], loff[256], bs[256], gsc[512];
    const int tid = threadIdx.x;

    if (blockIdx.x < 512) {
        // ---------------- build branch (unchanged) ----------------
        const int b = blockIdx.x;
        for (int i = tid; i < 512; i += 256) gsc[i] = bhist[i];
        __syncthreads();
        for (int d = 1; d < 512; d <<= 1) {
            int i1 = tid + 256;
            int t0 = (tid >= d) ? gsc[tid - d] : 0;
            int t1 = gsc[i1 - d];
            __syncthreads();
            gsc[tid] += t0; gsc[i1] += t1;
            __syncthreads();
        }
        const int size  = bhist[b];
        const int start = gsc[b] - size;      // exclusive
        lcnt[tid] = 0;
        __syncthreads();
        for (int i = tid; i < size; i += 256)
            atomicAdd(&lcnt[(pairs[start + i] >> 16) & 255], 1);
        __syncthreads();
        int s = lcnt[tid];
        bs[tid] = s;
        __syncthreads();
        for (int d = 1; d < 256; d <<= 1) {
            int t = (tid >= d) ? bs[tid - d] : 0;
            __syncthreads();
            bs[tid] += t;
            __syncthreads();
        }
        const int P = bs[tid] - s;
        const int seg = (b < 256) ? (b * 256 + tid) : (NKW + (b - 256) * 256 + tid);
        off[seg] = start + P;
        cnt[seg] = s;
        dis[seg] = rsqrtf((float)(s + 1));
        loff[tid] = P;
        lcnt[tid] = 0;
        __syncthreads();
        for (int i = tid; i < size; i += 256) {
            u32 p = pairs[start + i];
            int key = (p >> 16) & 255;
            int r = atomicAdd(&lcnt[key], 1);
            csr[start + loff[key] + r] = (int)(p & 0xFFFF);
        }
        return;
    }

    // ---------------- layer-0 GEMM branch (unchanged) ----------------
    const int blk = blockIdx.x - 512;
    const int w = tid >> 6, l = tid & 63, lr = l & 15, q = l >> 4;
    const int row = blk * 64 + w * 16 + lr;
    f32x4 acc[8];
    #pragma unroll
    for (int ct = 0; ct < 8; ++ct) acc[ct] = (f32x4){0.f, 0.f, 0.f, 0.f};
    #pragma unroll
    for (int kc = 0; kc < 4; ++kc) {
        U8 a;
        const int kb = kc * 32 + 4 * q;
        const float* A = Xn + (size_t)row * 128;
        f32x4 lo = *(const f32x4*)(A + kb);
        f32x4 hi = *(const f32x4*)(A + kb + 16);
        #pragma unroll
        for (int i = 0; i < 4; ++i) {
            a.s[i]     = (short)f2bf(lo[i]);
            a.s[4 + i] = (short)f2bf(hi[i]);
        }
        #pragma unroll
        for (int ct = 0; ct < 8; ++ct)
            acc[ct] = __builtin_amdgcn_mfma_f32_16x16x32_bf16(
                          a.v, wfb[WOFF_W0 + (kc * 8 + ct) * 64 + l], acc[ct], 0, 0, 0);
    }
    const int orow0 = blk * 64 + w * 16 + 4 * q;
    #pragma unroll
    for (int ct = 0; ct < 8; ++ct) {
        const int col = ct * 16 + lr;
        const float bb = b0[col];
        #pragma unroll
        for (int r = 0; r < 4; ++r) {
            float v = fmaxf(acc[ct][r] + bb, 0.f);
            h0f8[(size_t)(orow0 + r) * 128 + col] = f2fp8(v);
        }
    }
}

// ================= agg: fp8 aggregation (16 lanes/row = one 128B line/edge) =====
template<bool KW_SIDE>
__global__ __launch_bounds__(256) void aggf8_k(
        const int* __restrict__ off, const int* __restrict__ cnt,
        const int* __restrict__ csr, const u8* __restrict__ gsrc,
        const u8* __restrict__ h0f8, const float* __restrict__ dis,
        u16* __restrict__ outb) {
    const int r    = blockIdx.x * 16 + (threadIdx.x >> 4);
    const int lane = threadIdx.x & 15;
    const int seg  = KW_SIDE ? r : (NKW + r);
    const int st = off[seg];
    const int n  = cnt[seg];
    float a[8];
    #pragma unroll
    for (int j = 0; j < 8; ++j) a[j] = 0.f;

    #define DECACC(vv) { \
        u32 lo_ = (u32)(vv), hi_ = (u32)((vv) >> 32); \
        f32x2 p0 = __builtin_amdgcn_cvt_pk_f32_fp8(lo_, false); \
        f32x2 p1 = __builtin_amdgcn_cvt_pk_f32_fp8(lo_, true);  \
        f32x2 p2 = __builtin_amdgcn_cvt_pk_f32_fp8(hi_, false); \
        f32x2 p3 = __builtin_amdgcn_cvt_pk_f32_fp8(hi_, true);  \
        a[0] += p0[0]; a[1] += p0[1]; a[2] += p1[0]; a[3] += p1[1]; \
        a[4] += p2[0]; a[5] += p2[1]; a[6] += p3[0]; a[7] += p3[1]; }

    int i = 0;
    for (; i + 8 <= n; i += 8) {                  // 8 gathers in flight
        int nb[8];
        #pragma unroll
        for (int k = 0; k < 8; ++k) nb[k] = csr[st + i + k];
        u64 v[8];
        #pragma unroll
        for (int k = 0; k < 8; ++k)
            v[k] = *(const u64*)(gsrc + (size_t)nb[k] * 128 + lane * 8);
        #pragma unroll
        for (int k = 0; k < 8; ++k) DECACC(v[k])
    }
    for (; i < n; ++i) {
        int nb = csr[st + i];
        u64 v = *(const u64*)(gsrc + (size_t)nb * 128 + lane * 8);
        DECACC(v)
    }
    #undef DECACC

    const float dk = dis[seg];
    if (KW_SIDE) {
        u64 hv = *(const u64*)(h0f8 + (size_t)r * 128 + lane * 8);
        u32 lo_ = (u32)hv, hi_ = (u32)(hv >> 32);
        f32x2 p0 = __builtin_amdgcn_cvt_pk_f32_fp8(lo_, false);
        f32x2 p1 = __builtin_amdgcn_cvt_pk_f32_fp8(lo_, true);
        f32x2 p2 = __builtin_amdgcn_cvt_pk_f32_fp8(hi_, false);
        f32x2 p3 = __builtin_amdgcn_cvt_pk_f32_fp8(hi_, true);
        float hh[8] = {p0[0], p0[1], p1[0], p1[1], p2[0], p2[1], p3[0], p3[1]};
        #pragma unroll
        for (int j = 0; j < 8; ++j) a[j] = dk * (a[j] + dk * hh[j]);
    } else {
        #pragma unroll
        for (int j = 0; j < 8; ++j) a[j] *= dk;
    }
    U8 o;
    #pragma unroll
    for (int j = 0; j < 8; ++j) o.s[j] = (short)f2bf(a[j]);
    *(short8*)(outb + (size_t)r * 128 + lane * 8) = o.v;
}

// ================= K7: layer-1 GEMM + g multiply; writes xdoc fp8 ===============
__global__ __launch_bounds__(256) void k7_gemm1g(
        const u16* __restrict__ aggin, const short8* __restrict__ wfb,
        const float* __restrict__ bg1, const u16* __restrict__ gmul,
        u8* __restrict__ xdocf8, float* __restrict__ outdoc) {
    const int tid = threadIdx.x;
    const int w = tid >> 6, l = tid & 63, lr = l & 15, q = l >> 4;
    const int row = blockIdx.x * 64 + w * 16 + lr;
    f32x4 acc[8];
    #pragma unroll
    for (int ct = 0; ct < 8; ++ct) acc[ct] = (f32x4){0.f, 0.f, 0.f, 0.f};
    #pragma unroll
    for (int kc = 0; kc < 4; ++kc) {
        U8 a;
        const int kb = kc * 32 + 4 * q;
        const u16* A = aggin + (size_t)row * 128;
        a.u[0] = *(const u64*)(A + kb);
        a.u[1] = *(const u64*)(A + kb + 16);
        #pragma unroll
        for (int ct = 0; ct < 8; ++ct)
            acc[ct] = __builtin_amdgcn_mfma_f32_16x16x32_bf16(
                          a.v, wfb[WOFF_WG1 + (kc * 8 + ct) * 64 + l], acc[ct], 0, 0, 0);
    }
    const int orow0 = blockIdx.x * 64 + w * 16 + 4 * q;
    #pragma unroll
    for (int ct = 0; ct < 8; ++ct) {
        const int col = ct * 16 + lr;
        const float bb = bg1[col];
        #pragma unroll
        for (int r = 0; r < 4; ++r) {
            float v = fmaxf(acc[ct][r] + bb, 0.f);
            const size_t idx = (size_t)(orow0 + r) * 128 + col;
            xdocf8[idx] = f2fp8(v);
            float o = v * bf2f(gmul[idx]);
            __builtin_nontemporal_store(o, outdoc + idx);
        }
    }
}

// ================= K8: layer-2 GEMM (bf16 in, fp32 out) =========================
__global__ __launch_bounds__(256) void k8_gemm2(
        const u16* __restrict__ Av, const short8* __restrict__ wfb,
        const float* __restrict__ bg2, float* __restrict__ outf32) {
    const int tid = threadIdx.x;
    const int w = tid >> 6, l = tid & 63, lr = l & 15, q = l >> 4;
    const int row = blockIdx.x * 64 + w * 16 + lr;
    f32x4 acc[8];
    #pragma unroll
    for (int ct = 0; ct < 8; ++ct) acc[ct] = (f32x4){0.f, 0.f, 0.f, 0.f};
    #pragma unroll
    for (int kc = 0; kc < 4; ++kc) {
        U8 a;
        const int kb = kc * 32 + 4 * q;
        const u16* A = Av + (size_t)row * 128;
        a.u[0] = *(const u64*)(A + kb);
        a.u[1] = *(const u64*)(A + kb + 16);
        #pragma unroll
        for (int ct = 0; ct < 8; ++ct)
            acc[ct] = __builtin_amdgcn_mfma_f32_16x16x32_bf16(
                          a.v, wfb[WOFF_WG2 + (kc * 8 + ct) * 64 + l], acc[ct], 0, 0, 0);
    }
    const int orow0 = blockIdx.x * 64 + w * 16 + 4 * q;
    #pragma unroll
    for (int ct = 0; ct < 8; ++ct) {
        const int col = ct * 16 + lr;
        const float bb = bg2[col];
        #pragma unroll
        for (int r = 0; r < 4; ++r) {
            float v = fmaxf(acc[ct][r] + bb, 0.f);
            __builtin_nontemporal_store(v, outf32 + (size_t)(orow0 + r) * 128 + col);
        }
    }
}

extern "C" void kernel_launch(void* const* d_in, const int* in_sizes, int n_in,
                              void* d_out, int out_size, void* d_ws, size_t ws_size,
                              hipStream_t stream) {
    const float* Xn  = (const float*)d_in[0];
    const float* Xfb = (const float*)d_in[1];
    const float* Xt  = (const float*)d_in[2];
    const int*   e01 = (const int*)d_in[3];
    const float* W0  = (const float*)d_in[6];
    const float* b0  = (const float*)d_in[7];
    const float* Wg1 = (const float*)d_in[8];
    const float* bg1 = (const float*)d_in[9];
    const float* Wg2 = (const float*)d_in[10];
    const float* bg2 = (const float*)d_in[11];
    const float* Wf1 = (const float*)d_in[12];
    const float* bf1 = (const float*)d_in[13];
    const float* Wf2 = (const float*)d_in[14];
    const float* bf2 = (const float*)d_in[15];
    const float* Wt1 = (const float*)d_in[16];
    const float* bt1 = (const float*)d_in[17];
    const float* Wt2 = (const float*)d_in[18];
    const float* bt2 = (const float*)d_in[19];

    float* out = (float*)d_out;
    char*  ws  = (char*)d_ws;
    u8*    bufA  = (u8*)(ws + BUFA_OFF);      // h0 fp8
    u8*    bufD  = (u8*)(ws + BUFD_OFF);      // xdoc fp8
    u16*   bufB  = (u16*)(ws + BUFB_OFF);     // g bf16
    u16*   bufC  = (u16*)(ws + BUFC_OFF);     // pairs -> agg outputs bf16
    u32*   pairs = (u32*)(ws + BUFC_OFF);
    short8* wfb  = (short8*)(ws + WF_OFF);
    int*   csr   = (int*)(ws + CSR_OFF);
    int*   cnt   = (int*)(ws + CNT_OFF);
    int*   bhist = (int*)(ws + AUX_OFF);
    int*   bfill = bhist + 512;
    int*   off   = (int*)(ws + OFF_OFF);
    float* dis   = (float*)(ws + DIS_OFF);

    const int* src = e01;
    const int* dst = e01 + NE;

    PrepArgs pa;
    pa.w[0] = W0;  pa.K[0] = 128;
    pa.w[1] = Wg1; pa.K[1] = 128;
    pa.w[2] = Wg2; pa.K[2] = 128;
    pa.w[3] = Wf1; pa.K[3] = 16;
    pa.w[4] = Wf2; pa.K[4] = 128;
    pa.w[5] = Wt1; pa.K[5] = 8;
    pa.w[6] = Wt2; pa.K[6] = 128;

    zero_k<<<4, 256, 0, stream>>>(bhist);                         // bhist + bfill
    k1_hist_prep<<<NBLK + 56, 256, 0, stream>>>(src, dst, bhist, pa, wfb);
    // part (256) + gates (1024): gates independent, fills idle CUs behind part
    k2_part_gates<<<NBLK + 1024, 256, 0, stream>>>(
        src, dst, bhist, bfill, pairs,
        wfb, Xfb, Xt, bf1, bf2, bt1, bt2, bufB);
    // build (512) + gemm0 (1024): gemm0 independent, fills idle CUs behind build
    k3_build_gemm0<<<512 + 1024, 256, 0, stream>>>(
        pairs, bhist, off, cnt, dis, csr, Xn, wfb, b0, bufA);

    // layer 1: agg(h0 fp8) -> bufC bf16; GEMM + g multiply -> out_doc + xdoc fp8
    aggf8_k<false><<<NDOC / 16, 256, 0, stream>>>(off, cnt, csr, bufA, nullptr, dis, bufC);
    k7_gemm1g<<<1024, 256, 0, stream>>>(bufC, wfb, bg1, bufB, bufD,
                                        out + (size_t)NKW * 128);

    // layer 2: agg(xdoc fp8) + dk^2*h0(fp8) -> bufC bf16; GEMM -> out_kw fp32
    aggf8_k<true><<<NKW / 16, 256, 0, stream>>>(off, cnt, csr, bufD, bufA, dis, bufC);
    k8_gemm2<<<1024, 256, 0, stream>>>(bufC, wfb, bg2, out);
}